// Round 1
// baseline (150.129 us; speedup 1.0000x reference)
//
#include <hip/hip_runtime.h>

#define NC 65
#define NCELL (NC * NC * NC)
#define NE 19
#define NF 8

// MT_TRI rows packed 4 bits per entry (0xF == -1), entry v at bits [4v,4v+4)
__constant__ unsigned MTP[16] = {
    0x00FFFFFFu, 0x00FFF210u, 0x00FFF430u, 0x00341421u,
    0x00FFF531u, 0x00350520u, 0x00450510u, 0x00FFF542u,
    0x00FFF542u, 0x00450510u, 0x00250530u, 0x00FFF531u,
    0x00241431u, 0x00FFF430u, 0x00FFF210u, 0x00FFFFFFu
};

// cell-edge endpoints (19 unique edges, discovery order of the reference)
__device__ constexpr int EA[NE] = {0,0,0,1,1,3,0,2,2,0,2,6,0,4,4,0,4,5,1};
__device__ constexpr int EB[NE] = {1,3,7,3,7,7,2,3,7,6,6,7,4,6,7,5,5,7,5};

// tets' corner ids
__device__ constexpr int TETSV[6][4] = {
    {0,1,3,7},{0,3,2,7},{0,2,6,7},{0,6,4,7},{0,4,5,7},{0,5,1,7}
};

// T2C rows packed 5 bits per entry: entry e at bits [5e,5e+5)
__device__ constexpr unsigned T2CP[6] = {
    0x0A418820u,  // [0,1,2,3,4,5]
    0x105388C1u,  // [1,6,2,7,5,8]
    0x16850926u,  // [6,9,2,10,8,11]
    0x1CB68989u,  // [9,12,2,13,11,14]
    0x22E809ECu,  // [12,15,2,16,14,17]
    0x0919080Fu   // [15,0,2,18,17,4]
};

// 4-byte-aligned float4: sub-buffer bases are only 4B aligned (odd float counts
// upstream), so declare align(4) and let the compiler emit legal stores.
typedef float float4u __attribute__((ext_vector_type(4), aligned(4)));

extern "C" __global__ void __launch_bounds__(256)
diffmc_kernel(const float* __restrict__ sdf, const float* __restrict__ feat,
              float* __restrict__ oV, float* __restrict__ oF, float* __restrict__ oT)
{
    int cell = blockIdx.x * 256 + threadIdx.x;
    if (cell >= NCELL) return;
    int k  = cell % NC;
    int t_ = cell / NC;
    int j  = t_ % NC;
    int i  = t_ / NC;

    // ---- load 8 corner sdf + 8x8 corner feats (on-the-fly padding) ----
    float  cs[8];
    float4 cfl[8], cfh[8];
#pragma unroll
    for (int c = 0; c < 8; ++c) {
        int x = i + (c & 1) - 1;
        int y = j + ((c >> 1) & 1) - 1;
        int z = k + ((c >> 2) & 1) - 1;
        bool inb = ((unsigned)x < 64u) && ((unsigned)y < 64u) && ((unsigned)z < 64u);
        if (inb) {
            int idx = (x * 64 + y) * 64 + z;
            cs[c] = sdf[idx];
            const float4* fp = (const float4*)(feat + (size_t)idx * NF);
            cfl[c] = fp[0];
            cfh[c] = fp[1];
        } else {
            cs[c]  = 1.0f;                      // pad value: isovalue + 1.0
            cfl[c] = make_float4(0.f, 0.f, 0.f, 0.f);
            cfh[c] = make_float4(0.f, 0.f, 0.f, 0.f);
        }
    }

    unsigned ins = 0;
#pragma unroll
    for (int c = 0; c < 8; ++c) ins |= (cs[c] < 0.0f ? 1u : 0u) << c;

    const float inv63 = 1.0f / 63.0f;
    size_t vbase = (size_t)cell * (NE * 3);
    size_t fbase = (size_t)cell * (NE * NF);

    // ---- 19 edges: verts + feats ----
#pragma unroll
    for (int e = 0; e < NE; ++e) {
        const int a = EA[e], b = EB[e];
        bool cross = (((ins >> a) & 1u) != ((ins >> b) & 1u));
        float sa = cs[a], sb = cs[b];
        float t = cross ? (-sa) / (sb - sa) : 0.0f;

        float pax = (float)(i + (a & 1)),        pbx = (float)(i + (b & 1));
        float pay = (float)(j + ((a >> 1) & 1)), pby = (float)(j + ((b >> 1) & 1));
        float paz = (float)(k + ((a >> 2) & 1)), pbz = (float)(k + ((b >> 2) & 1));

        // where(cross, lerp, 0), THEN (v - 1)/63  (matches reference order)
        float vx = cross ? pax + t * (pbx - pax) : 0.0f;
        float vy = cross ? pay + t * (pby - pay) : 0.0f;
        float vz = cross ? paz + t * (pbz - paz) : 0.0f;
        oV[vbase + e * 3 + 0] = (vx - 1.0f) * inv63;
        oV[vbase + e * 3 + 1] = (vy - 1.0f) * inv63;
        oV[vbase + e * 3 + 2] = (vz - 1.0f) * inv63;

        float4u fl, fh;
        fl.x = cross ? cfl[a].x + t * (cfl[b].x - cfl[a].x) : 0.0f;
        fl.y = cross ? cfl[a].y + t * (cfl[b].y - cfl[a].y) : 0.0f;
        fl.z = cross ? cfl[a].z + t * (cfl[b].z - cfl[a].z) : 0.0f;
        fl.w = cross ? cfl[a].w + t * (cfl[b].w - cfl[a].w) : 0.0f;
        fh.x = cross ? cfh[a].x + t * (cfh[b].x - cfh[a].x) : 0.0f;
        fh.y = cross ? cfh[a].y + t * (cfh[b].y - cfh[a].y) : 0.0f;
        fh.z = cross ? cfh[a].z + t * (cfh[b].z - cfh[a].z) : 0.0f;
        fh.w = cross ? cfh[a].w + t * (cfh[b].w - cfh[a].w) : 0.0f;
        *(float4u*)(oF + fbase + e * NF)     = fl;
        *(float4u*)(oF + fbase + e * NF + 4) = fh;
    }

    // ---- 6 tets x 6 entries: triangle indices (written as float values) ----
    float tout[36];
    int cell19 = cell * 19;
#pragma unroll
    for (int ti = 0; ti < 6; ++ti) {
        const int c0 = TETSV[ti][0], c1 = TETSV[ti][1], c2 = TETSV[ti][2], c3 = TETSV[ti][3];
        int cse = (int)(((ins >> c0) & 1u)
                 | (((ins >> c1) & 1u) << 1)
                 | (((ins >> c2) & 1u) << 2)
                 | (((ins >> c3) & 1u) << 3));
        unsigned m  = MTP[cse];
        unsigned tp = T2CP[ti];   // compile-time constant (loop unrolled)
#pragma unroll
        for (int v = 0; v < 6; ++v) {
            int lt = (int)((m >> (4 * v)) & 0xFu);
            int lc = (lt == 15) ? 0 : lt;          // clip(ltri, 0)
            int ce = (int)((tp >> (5 * lc)) & 31u);
            tout[ti * 6 + v] = (lt == 15) ? -1.0f : (float)(cell19 + ce);
        }
    }
    size_t tbase = (size_t)cell * 36;
#pragma unroll
    for (int q = 0; q < 9; ++q) {
        float4u tq;
        tq.x = tout[q * 4 + 0];
        tq.y = tout[q * 4 + 1];
        tq.z = tout[q * 4 + 2];
        tq.w = tout[q * 4 + 3];
        *(float4u*)(oT + tbase + q * 4) = tq;
    }
}

extern "C" void kernel_launch(void* const* d_in, const int* in_sizes, int n_in,
                              void* d_out, int out_size, void* d_ws, size_t ws_size,
                              hipStream_t stream) {
    const float* sdf  = (const float*)d_in[0];
    const float* feat = (const float*)d_in[1];
    float* out = (float*)d_out;
    float* oV = out;
    float* oF = oV + (size_t)NCELL * NE * 3;
    float* oT = oF + (size_t)NCELL * NE * NF;
    int blocks = (NCELL + 255) / 256;
    diffmc_kernel<<<blocks, 256, 0, stream>>>(sdf, feat, oV, oF, oT);
}

// Round 2
// 98.968 us; speedup vs baseline: 1.5169x; 1.5169x over previous
//
#include <hip/hip_runtime.h>

#define NC 65
#define NCELL 274625
#define NE 19
#define NF 8

// MT_TRI rows packed 4 bits per entry (0xF == -1), entry v at bits [4v,4v+4)
__constant__ unsigned MTP[16] = {
    0x00FFFFFFu, 0x00FFF210u, 0x00FFF430u, 0x00341421u,
    0x00FFF531u, 0x00350520u, 0x00450510u, 0x00FFF542u,
    0x00FFF542u, 0x00450510u, 0x00250530u, 0x00FFF531u,
    0x00241431u, 0x00FFF430u, 0x00FFF210u, 0x00FFFFFFu
};

// cell-edge endpoints (19 unique edges, reference discovery order)
__device__ constexpr int EA[NE] = {0,0,0,1,1,3,0,2,2,0,2,6,0,4,4,0,4,5,1};
__device__ constexpr int EB[NE] = {1,3,7,3,7,7,2,3,7,6,6,7,4,6,7,5,5,7,5};

__device__ constexpr int TETSV[6][4] = {
    {0,1,3,7},{0,3,2,7},{0,2,6,7},{0,6,4,7},{0,4,5,7},{0,5,1,7}
};

// T2C rows packed 5 bits per entry: entry e at bits [5e,5e+5)
__device__ constexpr unsigned T2CP[6] = {
    0x0A418820u, 0x105388C1u, 0x16850926u,
    0x1CB68989u, 0x22E809ECu, 0x0919080Fu
};

// LDS staging buffer: max(128*57, 64*153, 256*37) = 9792 dwords = 39168 B
// -> 4 blocks/CU (156.7 KB of 160 KB). Strides 57/153/37 are odd -> no bank
// conflicts on the strided per-cell writes.
#define LDSW 9792

extern "C" __global__ void __launch_bounds__(256, 4)
diffmc_kernel(const float* __restrict__ sdf, const float* __restrict__ feat,
              float* __restrict__ oV, float* __restrict__ oF, float* __restrict__ oT)
{
    __shared__ float lds[LDSW];
    const int tid = threadIdx.x;
    const int blockBase = blockIdx.x << 8;
    const int cell = blockBase + tid;
    const bool valid = cell < NCELL;
    const int cc = valid ? cell : 0;
    const int k  = cc % NC;
    const int t_ = cc / NC;
    const int j  = t_ % NC;
    const int i  = t_ / NC;

    // ---- corner SDF + per-edge t (held in regs across phases) ----
    float cs[8];
#pragma unroll
    for (int c = 0; c < 8; ++c) {
        int x = i + (c & 1) - 1;
        int y = j + ((c >> 1) & 1) - 1;
        int z = k + ((c >> 2) & 1) - 1;
        bool inb = ((unsigned)x < 64u) & ((unsigned)y < 64u) & ((unsigned)z < 64u);
        cs[c] = inb ? sdf[(x * 64 + y) * 64 + z] : 1.0f;   // pad = iso + 1
    }
    unsigned ins = 0;
#pragma unroll
    for (int c = 0; c < 8; ++c) ins |= (cs[c] < 0.0f ? 1u : 0u) << c;

    float t19[NE];
    unsigned crossm = 0;
#pragma unroll
    for (int e = 0; e < NE; ++e) {
        const int a = EA[e], b = EB[e];
        bool cross = (((ins >> a) ^ (ins >> b)) & 1u) != 0u;
        t19[e] = cross ? (-cs[a]) / (cs[b] - cs[a]) : 0.0f;
        crossm |= (cross ? 1u : 0u) << e;
    }

    const float inv63 = 1.0f / 63.0f;

    // ================= verts: 2 sub-phases x 128 cells =================
#pragma unroll 1
    for (int s = 0; s < 2; ++s) {
        const int c0 = s << 7;
        if (valid && (unsigned)(tid - c0) < 128u) {
            float* Lb = lds + (tid - c0) * 57;
#pragma unroll
            for (int e = 0; e < NE; ++e) {
                const int a = EA[e], b = EB[e];
                bool cross = (crossm >> e) & 1u;
                float t = t19[e];
                float pax = (float)(i + (a & 1)),       pbx = (float)(i + (b & 1));
                float pay = (float)(j + ((a >> 1) & 1)), pby = (float)(j + ((b >> 1) & 1));
                float paz = (float)(k + ((a >> 2) & 1)), pbz = (float)(k + ((b >> 2) & 1));
                float vx = cross ? pax + t * (pbx - pax) : 0.0f;
                float vy = cross ? pay + t * (pby - pay) : 0.0f;
                float vz = cross ? paz + t * (pbz - paz) : 0.0f;
                Lb[e * 3 + 0] = (vx - 1.0f) * inv63;
                Lb[e * 3 + 1] = (vy - 1.0f) * inv63;
                Lb[e * 3 + 2] = (vz - 1.0f) * inv63;
            }
        }
        __syncthreads();
        int vc = NCELL - (blockBase + c0);
        vc = vc < 0 ? 0 : (vc > 128 ? 128 : vc);
        const int nd = vc * 57;
        float* dst = oV + (size_t)(blockBase + c0) * 57;
        for (int p = tid; p < nd; p += 256) dst[p] = lds[p];   // lane-consecutive
        __syncthreads();
    }

    // ================= feats: 4 sub-phases x 64 cells =================
#pragma unroll 1
    for (int s = 0; s < 4; ++s) {
        const int c0 = s << 6;
        if (valid && (unsigned)(tid - c0) < 64u) {
            float4 cfl[8], cfh[8];
#pragma unroll
            for (int c = 0; c < 8; ++c) {
                int x = i + (c & 1) - 1;
                int y = j + ((c >> 1) & 1) - 1;
                int z = k + ((c >> 2) & 1) - 1;
                bool inb = ((unsigned)x < 64u) & ((unsigned)y < 64u) & ((unsigned)z < 64u);
                if (inb) {
                    const float4* fp = (const float4*)(feat + (size_t)((x * 64 + y) * 64 + z) * NF);
                    cfl[c] = fp[0];
                    cfh[c] = fp[1];
                } else {
                    cfl[c] = make_float4(0.f, 0.f, 0.f, 0.f);
                    cfh[c] = make_float4(0.f, 0.f, 0.f, 0.f);
                }
            }
            float* Lb = lds + (tid - c0) * 153;
#pragma unroll
            for (int e = 0; e < NE; ++e) {
                const int a = EA[e], b = EB[e];
                bool cross = (crossm >> e) & 1u;
                float t = t19[e];
                Lb[e * 8 + 0] = cross ? cfl[a].x + t * (cfl[b].x - cfl[a].x) : 0.0f;
                Lb[e * 8 + 1] = cross ? cfl[a].y + t * (cfl[b].y - cfl[a].y) : 0.0f;
                Lb[e * 8 + 2] = cross ? cfl[a].z + t * (cfl[b].z - cfl[a].z) : 0.0f;
                Lb[e * 8 + 3] = cross ? cfl[a].w + t * (cfl[b].w - cfl[a].w) : 0.0f;
                Lb[e * 8 + 4] = cross ? cfh[a].x + t * (cfh[b].x - cfh[a].x) : 0.0f;
                Lb[e * 8 + 5] = cross ? cfh[a].y + t * (cfh[b].y - cfh[a].y) : 0.0f;
                Lb[e * 8 + 6] = cross ? cfh[a].z + t * (cfh[b].z - cfh[a].z) : 0.0f;
                Lb[e * 8 + 7] = cross ? cfh[a].w + t * (cfh[b].w - cfh[a].w) : 0.0f;
            }
        }
        __syncthreads();
        int vc = NCELL - (blockBase + c0);
        vc = vc < 0 ? 0 : (vc > 64 ? 64 : vc);
        const int nd = vc * 152;
        float* dst = oF + (size_t)(blockBase + c0) * 152;
        for (int p = tid; p < nd; p += 256) {
            int lc = (int)((unsigned)p / 152u);
            dst[p] = lds[lc * 153 + (p - lc * 152)];
        }
        __syncthreads();
    }

    // ================= tris =================
    if (valid) {
        float* Lb = lds + tid * 37;
        const int cell19 = cell * 19;
#pragma unroll
        for (int ti = 0; ti < 6; ++ti) {
            const int c0 = TETSV[ti][0], c1 = TETSV[ti][1], c2 = TETSV[ti][2], c3 = TETSV[ti][3];
            int cse = (int)(((ins >> c0) & 1u)
                     | (((ins >> c1) & 1u) << 1)
                     | (((ins >> c2) & 1u) << 2)
                     | (((ins >> c3) & 1u) << 3));
            unsigned m  = MTP[cse];
            unsigned tp = T2CP[ti];
#pragma unroll
            for (int v = 0; v < 6; ++v) {
                int lt = (int)((m >> (4 * v)) & 0xFu);
                int lc = (lt == 15) ? 0 : lt;
                int ce = (int)((tp >> (5 * lc)) & 31u);
                Lb[ti * 6 + v] = (lt == 15) ? -1.0f : (float)(cell19 + ce);
            }
        }
    }
    __syncthreads();
    {
        int vc = NCELL - blockBase;
        vc = vc < 0 ? 0 : (vc > 256 ? 256 : vc);
        const int nd = vc * 36;
        float* dst = oT + (size_t)blockBase * 36;
        for (int p = tid; p < nd; p += 256) {
            int lc = (int)((unsigned)p / 36u);
            dst[p] = lds[lc * 37 + (p - lc * 36)];
        }
    }
}

extern "C" void kernel_launch(void* const* d_in, const int* in_sizes, int n_in,
                              void* d_out, int out_size, void* d_ws, size_t ws_size,
                              hipStream_t stream) {
    const float* sdf  = (const float*)d_in[0];
    const float* feat = (const float*)d_in[1];
    float* out = (float*)d_out;
    float* oV = out;
    float* oF = oV + (size_t)NCELL * NE * 3;
    float* oT = oF + (size_t)NCELL * NE * NF;
    int blocks = (NCELL + 255) / 256;
    diffmc_kernel<<<blocks, 256, 0, stream>>>(sdf, feat, oV, oF, oT);
}

// Round 3
// 56.991 us; speedup vs baseline: 2.6342x; 1.7366x over previous
//
#include <hip/hip_runtime.h>

#define NC 65
#define NCELL 274625
#define NE 19
#define NF 8

// MT_TRI rows packed 4 bits per entry (0xF == -1), entry v at bits [4v,4v+4)
__constant__ unsigned MTP[16] = {
    0x00FFFFFFu, 0x00FFF210u, 0x00FFF430u, 0x00341421u,
    0x00FFF531u, 0x00350520u, 0x00450510u, 0x00FFF542u,
    0x00FFF542u, 0x00450510u, 0x00250530u, 0x00FFF531u,
    0x00241431u, 0x00FFF430u, 0x00FFF210u, 0x00FFFFFFu
};

// T2C rows packed 5 bits per entry: entry e at bits [5e,5e+5)
__constant__ unsigned T2CPc[6] = {
    0x0A418820u, 0x105388C1u, 0x16850926u,
    0x1CB68989u, 0x22E809ECu, 0x0919080Fu
};

// cell-edge endpoints (reference discovery order), compile-time arrays for
// the unrolled phase-0 loop:
__device__ constexpr int EA[NE] = {0,0,0,1,1,3,0,2,2,0,2,6,0,4,4,0,4,5,1};
__device__ constexpr int EB[NE] = {1,3,7,3,7,7,2,3,7,6,6,7,4,6,7,5,5,7,5};
// Same tables bit-packed (3 bits per edge at bits [3e,3e+3)) for runtime e:
#define EAP 0x006C120C82419200ULL
#define EBP 0x017D294FB76BF7D9ULL
// Tets: corner0 = 0 and corner3 = 7 for ALL tets; pack (c1 | c2<<3) per tet
// at bits [6*ti, 6*ti+6):
#define TETP 0x36C9B24D9ULL

extern "C" __global__ void __launch_bounds__(256, 4)
diffmc_kernel(const float* __restrict__ sdf, const float* __restrict__ feat,
              float* __restrict__ oV, float* __restrict__ oF, float* __restrict__ oT)
{
    // per-cell state table: 19 t-values + inside-mask, stride 21 (odd -> no
    // bank conflicts on the strided phase-0 writes). 21504 B total.
    __shared__ float lds[256 * 21];
    const int tid = threadIdx.x;
    const int blockBase = blockIdx.x << 8;
    int vc = NCELL - blockBase;
    vc = vc > 256 ? 256 : vc;

    // ---------------- phase 0: per-cell t19 + inside mask ----------------
    if (tid < vc) {
        const int cell = blockBase + tid;
        const int k  = cell % NC;
        const int t_ = cell / NC;
        const int j  = t_ % NC;
        const int i  = t_ / NC;
        float cs[8];
#pragma unroll
        for (int c = 0; c < 8; ++c) {
            int x = i + (c & 1) - 1;
            int y = j + ((c >> 1) & 1) - 1;
            int z = k + ((c >> 2) & 1) - 1;
            bool inb = ((unsigned)x < 64u) & ((unsigned)y < 64u) & ((unsigned)z < 64u);
            cs[c] = inb ? sdf[(x * 64 + y) * 64 + z] : 1.0f;   // pad = iso + 1
        }
        unsigned ins = 0;
#pragma unroll
        for (int c = 0; c < 8; ++c) ins |= (cs[c] < 0.0f ? 1u : 0u) << c;
        float* Ld = lds + tid * 21;
#pragma unroll
        for (int e = 0; e < NE; ++e) {
            const int a = EA[e], b = EB[e];
            bool cross = ((ins >> a) ^ (ins >> b)) & 1u;
            Ld[e] = cross ? (-cs[a]) / (cs[b] - cs[a]) : 0.0f;
        }
        Ld[19] = __uint_as_float(ins);
    }
    __syncthreads();

    const float inv63 = 1.0f / 63.0f;

    // -------- fused verts+feats: output-centric, one edge per iteration ----
    {
        const int nE = vc * NE;                       // 4864 for full blocks
        float* __restrict__ dV = oV + (size_t)blockBase * 57;
        float* __restrict__ dF = oF + (size_t)blockBase * 152;
        for (int E = tid; E < nE; E += 256) {
            const unsigned c = (unsigned)E / 19u;
            const unsigned e = (unsigned)E - c * 19u;
            const int cell = blockBase + (int)c;
            const unsigned kk = (unsigned)cell % 65u;
            const unsigned tq = (unsigned)cell / 65u;
            const unsigned jj = tq % 65u;
            const unsigned ii = tq / 65u;

            const float    t   = lds[c * 21 + e];
            const unsigned ins = __float_as_uint(lds[c * 21 + 19]);
            const unsigned a = (unsigned)(EAP >> (3u * e)) & 7u;
            const unsigned b = (unsigned)(EBP >> (3u * e)) & 7u;
            const bool cross = (((ins >> a) ^ (ins >> b)) & 1u) != 0u;

            // verts: where(cross, lerp, 0) THEN (v-1)/63 (reference order)
            const float pax = (float)(int)(ii + (a & 1u));
            const float pbx = (float)(int)(ii + (b & 1u));
            const float pay = (float)(int)(jj + ((a >> 1) & 1u));
            const float pby = (float)(int)(jj + ((b >> 1) & 1u));
            const float paz = (float)(int)(kk + ((a >> 2) & 1u));
            const float pbz = (float)(int)(kk + ((b >> 2) & 1u));
            const float vx = cross ? pax + t * (pbx - pax) : 0.0f;
            const float vy = cross ? pay + t * (pby - pay) : 0.0f;
            const float vz = cross ? paz + t * (pbz - paz) : 0.0f;
            const size_t vo = (size_t)c * 57 + e * 3u;
            dV[vo + 0] = (vx - 1.0f) * inv63;
            dV[vo + 1] = (vy - 1.0f) * inv63;
            dV[vo + 2] = (vz - 1.0f) * inv63;

            // feats: gather two corners' 8 floats (L1-resident grid), lerp
            const int xa = (int)ii + (int)(a & 1u) - 1;
            const int ya = (int)jj + (int)((a >> 1) & 1u) - 1;
            const int za = (int)kk + (int)((a >> 2) & 1u) - 1;
            const int xb = (int)ii + (int)(b & 1u) - 1;
            const int yb = (int)jj + (int)((b >> 1) & 1u) - 1;
            const int zb = (int)kk + (int)((b >> 2) & 1u) - 1;
            const bool iba = ((unsigned)xa < 64u) & ((unsigned)ya < 64u) & ((unsigned)za < 64u);
            const bool ibb = ((unsigned)xb < 64u) & ((unsigned)yb < 64u) & ((unsigned)zb < 64u);
            float4 fa0 = make_float4(0.f, 0.f, 0.f, 0.f), fa1 = fa0;
            float4 fb0 = fa0, fb1 = fa0;
            if (iba) {
                const float4* fp = (const float4*)(feat + (size_t)((xa * 64 + ya) * 64 + za) * NF);
                fa0 = fp[0]; fa1 = fp[1];
            }
            if (ibb) {
                const float4* fp = (const float4*)(feat + (size_t)((xb * 64 + yb) * 64 + zb) * NF);
                fb0 = fp[0]; fb1 = fp[1];
            }
            const size_t fo = (size_t)c * 152 + e * 8u;
            dF[fo + 0] = cross ? fa0.x + t * (fb0.x - fa0.x) : 0.0f;
            dF[fo + 1] = cross ? fa0.y + t * (fb0.y - fa0.y) : 0.0f;
            dF[fo + 2] = cross ? fa0.z + t * (fb0.z - fa0.z) : 0.0f;
            dF[fo + 3] = cross ? fa0.w + t * (fb0.w - fa0.w) : 0.0f;
            dF[fo + 4] = cross ? fa1.x + t * (fb1.x - fa1.x) : 0.0f;
            dF[fo + 5] = cross ? fa1.y + t * (fb1.y - fa1.y) : 0.0f;
            dF[fo + 6] = cross ? fa1.z + t * (fb1.z - fa1.z) : 0.0f;
            dF[fo + 7] = cross ? fa1.w + t * (fb1.w - fa1.w) : 0.0f;
        }
    }

    // ---------------- tris: one tet per iteration ----------------
    {
        const int nT = vc * 6;
        float* __restrict__ dT = oT + (size_t)blockBase * 36;
        for (int T = tid; T < nT; T += 256) {
            const unsigned c  = (unsigned)T / 6u;
            const unsigned ti = (unsigned)T - c * 6u;
            const unsigned ins = __float_as_uint(lds[c * 21 + 19]);
            const unsigned tc = (unsigned)(TETP >> (6u * ti)) & 63u;
            const unsigned c1 = tc & 7u, c2 = tc >> 3;
            const unsigned cse = (ins & 1u)
                               | (((ins >> c1) & 1u) << 1)
                               | (((ins >> c2) & 1u) << 2)
                               | (((ins >> 7) & 1u) << 3);
            const unsigned m  = MTP[cse];
            const unsigned tp = T2CPc[ti];
            const int cell19 = (blockBase + (int)c) * 19;
            const size_t to = (size_t)c * 36 + ti * 6u;
#pragma unroll
            for (int v = 0; v < 6; ++v) {
                const unsigned lt = (m >> (4 * v)) & 0xFu;
                const unsigned lc = (lt == 15u) ? 0u : lt;
                const unsigned ce = (tp >> (5 * lc)) & 31u;
                dT[to + v] = (lt == 15u) ? -1.0f : (float)(cell19 + (int)ce);
            }
        }
    }
}

extern "C" void kernel_launch(void* const* d_in, const int* in_sizes, int n_in,
                              void* d_out, int out_size, void* d_ws, size_t ws_size,
                              hipStream_t stream) {
    const float* sdf  = (const float*)d_in[0];
    const float* feat = (const float*)d_in[1];
    float* out = (float*)d_out;
    float* oV = out;
    float* oF = oV + (size_t)NCELL * NE * 3;
    float* oT = oF + (size_t)NCELL * NE * NF;
    int blocks = (NCELL + 255) / 256;
    diffmc_kernel<<<blocks, 256, 0, stream>>>(sdf, feat, oV, oF, oT);
}